// Round 2
// baseline (235.397 us; speedup 1.0000x reference)
//
#include <hip/hip_runtime.h>
#include <hip/hip_bf16.h>
#include <math.h>

// B,T,E,WIN,OC,VOCAB = 256,2048,128,5,128,50000
#define B_   256
#define T_   2048
#define E_   128
#define WIN_ 5
#define PAD_ 2
#define OC_  128
#define VOCAB_MAX 50000
#define VOCAB1 50001
#define TT   64
#define REAL_ROWS (TT + WIN_ - 1)
#define ROWS 80
#define ASTR 136                  // LDS row stride (bf16): 272B -> 2-way alias = free
#define VROWS 64                  // vocab rows per phase-A tile
#define NBLK_A ((VOCAB1 + VROWS - 1) / VROWS)   // 782 active phase-A blocks
#define BT   512                  // tokens per phase-B block
#define NBLK 1024                 // fused grid: 4 t-tiles x 256 batches; 4 blocks/CU exactly

typedef __attribute__((ext_vector_type(8))) short short8;
typedef __attribute__((ext_vector_type(4))) float floatx4;
typedef __attribute__((ext_vector_type(4))) unsigned uintx4;

static __device__ __forceinline__ short f2bf(float f) {
    union { __hip_bfloat16 h; short s; } u;
    u.h = __float2bfloat16(f);
    return u.s;
}

__device__ __forceinline__ void atomicMaxFloat(float* addr, float v) {
    // requires init to -inf: works on both sign paths
    if (v >= 0.0f) atomicMax((int*)addr, __float_as_int(v));
    else           atomicMin((unsigned int*)addr, __float_as_uint(v));
}

// ============ FUSED: build tables (phase A) + grid barrier + score/max (phase B) ============
// Phase A (blocks 0..781): D[v][o] = <emb[v],cnn_w[o]> bf16; r[v][k] = <emb[v],att_w[k]> f32.
// Phase B (all 1024 blocks): per (b, t-tile): r-gather -> window-sum -> sigmoid -> D-gather max.
// Grid barrier: device-scope atomic counter in ws (zeroed by hipMemsetAsync before launch).
// Residency proof: LDS 36.9KB <= 40KB @ 4 blk/CU, launch_bounds(256,4) caps VGPR at 128,
// 1024 blocks == 256 CU x 4 -> all blocks co-resident, barrier cannot deadlock.
__launch_bounds__(256, 4)
__global__ void fused_all(const int* __restrict__ x,
                          const float* __restrict__ emb,
                          const float* __restrict__ cnn_w,
                          const float* __restrict__ att_w,
                          const float* __restrict__ att_b_p,
                          const float* __restrict__ cnn_b,
                          short* __restrict__ D,
                          float* __restrict__ r,
                          unsigned* __restrict__ bar,
                          float* __restrict__ out) {
    __shared__ __align__(16) short sh_a[VROWS * ASTR];   // 17408 B (A: emb tile | B: rt/sc/red)
    __shared__ __align__(16) short sh_d[VROWS * ASTR];   // 17408 B (A: D staging)
    __shared__ int sh_x[BT + 4];                          // 2064 B  (persists A->B)

    const int tid  = threadIdx.x;
    const int lane = tid & 63;
    const int w    = tid >> 6;
    const int l15  = lane & 15;
    const int quad = lane >> 4;
    const int bid  = blockIdx.x;

    // phase-B identity
    const int b  = bid >> 2;
    const int t0 = (bid & 3) * BT;

    // ---- phase-B preload (independent of tables): token indices ----
    for (int i = tid; i < BT + 4; i += 256) {
        int t = t0 + i - PAD_;
        sh_x[i] = (t >= 0 && t < T_) ? x[b * T_ + t] : -1;
    }

    // ================= phase A =================
    if (bid < NBLK_A) {
        const int v0 = bid * VROWS;

        if (bid < (B_ * OC_) / 256)
            out[bid * 256 + tid] = -INFINITY;

        // stage 64 vocab rows fp32 -> bf16 (coalesced; clamp OOB rows)
        #pragma unroll
        for (int t = 0; t < 8; t++) {
            int i   = t * 256 + tid;
            int row = i >> 5, c4 = i & 31;
            int vr  = v0 + row; if (vr > VOCAB_MAX) vr = VOCAB_MAX;
            float4 v = *(const float4*)(emb + (size_t)vr * E_ + c4 * 4);
            short4 o; o.x = f2bf(v.x); o.y = f2bf(v.y); o.z = f2bf(v.z); o.w = f2bf(v.w);
            *(short4*)(&sh_a[row * ASTR + c4 * 4]) = o;
        }

        // B fragments (cnn_w fp32 -> bf16): wave w -> cols [w*32, w*32+32)
        short8 Bf[2][4];
        #pragma unroll
        for (int j = 0; j < 2; j++)
            #pragma unroll
            for (int ks = 0; ks < 4; ks++) {
                const float4* p = (const float4*)(cnn_w + (size_t)(w * 32 + j * 16 + l15) * E_ + ks * 32 + quad * 8);
                float4 p0 = p[0], p1 = p[1];
                Bf[j][ks] = (short8){ f2bf(p0.x), f2bf(p0.y), f2bf(p0.z), f2bf(p0.w),
                                      f2bf(p1.x), f2bf(p1.y), f2bf(p1.z), f2bf(p1.w) };
            }

        // att-tap fragments (taps >= WIN_ are zero)
        short8 Ba[4];
        #pragma unroll
        for (int ks = 0; ks < 4; ks++) {
            short8 v = (short8){0,0,0,0,0,0,0,0};
            if (l15 < WIN_) {
                const float4* p = (const float4*)(att_w + (size_t)l15 * E_ + ks * 32 + quad * 8);
                float4 p0 = p[0], p1 = p[1];
                v = (short8){ f2bf(p0.x), f2bf(p0.y), f2bf(p0.z), f2bf(p0.w),
                              f2bf(p1.x), f2bf(p1.y), f2bf(p1.z), f2bf(p1.w) };
            }
            Ba[ks] = v;
        }
        __syncthreads();

        // D tiles: 4 m-tiles x 2 n-tiles per wave -> stage into sh_d
        #pragma unroll
        for (int mt = 0; mt < 4; mt++) {
            short8 a[4];
            #pragma unroll
            for (int ks = 0; ks < 4; ks++)
                a[ks] = *(const short8*)(&sh_a[(mt * 16 + l15) * ASTR + ks * 32 + quad * 8]);
            #pragma unroll
            for (int j = 0; j < 2; j++) {
                floatx4 acc = (floatx4){0.f, 0.f, 0.f, 0.f};
                #pragma unroll
                for (int ks = 0; ks < 4; ks++)
                    acc = __builtin_amdgcn_mfma_f32_16x16x32_bf16(a[ks], Bf[j][ks], acc, 0, 0, 0);
                #pragma unroll
                for (int rr = 0; rr < 4; rr++)
                    sh_d[(mt * 16 + quad * 4 + rr) * ASTR + w * 32 + j * 16 + l15] = f2bf(acc[rr]);
            }
        }

        // r tile: wave w handles m-tile w
        {
            short8 a[4];
            #pragma unroll
            for (int ks = 0; ks < 4; ks++)
                a[ks] = *(const short8*)(&sh_a[(w * 16 + l15) * ASTR + ks * 32 + quad * 8]);
            floatx4 acc = (floatx4){0.f, 0.f, 0.f, 0.f};
            #pragma unroll
            for (int ks = 0; ks < 4; ks++)
                acc = __builtin_amdgcn_mfma_f32_16x16x32_bf16(a[ks], Ba[ks], acc, 0, 0, 0);
            if (l15 < 8) {
                #pragma unroll
                for (int rr = 0; rr < 4; rr++) {
                    int v = v0 + w * 16 + quad * 4 + rr;
                    if (v <= VOCAB_MAX) r[(size_t)v * 8 + l15] = acc[rr];
                }
            }
        }
        __syncthreads();

        // coalesced D store: thread covers 4 x 16-B chunks (dwordx4)
        #pragma unroll
        for (int st = 0; st < 4; st++) {
            int i   = st * 256 + tid;
            int row = i >> 4, c = i & 15;
            int v   = v0 + row;
            if (v <= VOCAB_MAX)
                *(short8*)(D + (size_t)v * E_ + c * 8) =
                    *(const short8*)(&sh_d[row * ASTR + c * 8]);
        }
    }

    // ================= grid barrier =================
    __syncthreads();
    if (tid == 0) {
        __threadfence();   // release: D/r/out-init visible device-wide
        __hip_atomic_fetch_add(bar, 1u, __ATOMIC_ACQ_REL, __HIP_MEMORY_SCOPE_AGENT);
        while (__hip_atomic_load(bar, __ATOMIC_RELAXED, __HIP_MEMORY_SCOPE_AGENT) < NBLK)
            __builtin_amdgcn_s_sleep(8);
        __threadfence();   // acquire
    }
    __syncthreads();

    // ================= phase B =================
    // LDS alias: carve rt/sc/red out of sh_a (4352 floats available; need 3624)
    float* sh_rt = (float*)sh_a;          // [5][BT+8] = 2600 floats
    float* sh_sc = sh_rt + 5 * (BT + 8);  // 512 floats
    float* sh_red = sh_sc + BT;           // [4][128] = 512 floats
    const int grp = lane >> 4;

    // r-gather into SoA LDS (uses preloaded sh_x)
    for (int i = tid; i < BT + 4; i += 256) {
        int v = sh_x[i];
        float4 r03 = make_float4(0.f, 0.f, 0.f, 0.f);
        float  r4  = 0.f;
        if (v >= 0) {
            r03 = *(const float4*)(r + (size_t)v * 8);
            r4  = r[(size_t)v * 8 + 4];
        }
        sh_rt[0 * (BT + 8) + i] = r03.x; sh_rt[1 * (BT + 8) + i] = r03.y;
        sh_rt[2 * (BT + 8) + i] = r03.z; sh_rt[3 * (BT + 8) + i] = r03.w;
        sh_rt[4 * (BT + 8) + i] = r4;
    }
    __syncthreads();

    const int base_t = w * 128;

    // prefetch batch 0 D-gathers — overlaps score phase
    uintx4 uA[8];
    #pragma unroll
    for (int j = 0; j < 8; j++) {
        int tok = base_t + j * 4 + grp;
        int v   = sh_x[tok + PAD_];
        uA[j]   = *(const uintx4*)(D + (size_t)v * E_ + l15 * 8);
    }

    // window-sum + sigmoid (LDS only)
    {
        const float attb = att_b_p[0];
        #pragma unroll
        for (int rep = 0; rep < 2; rep++) {
            int j = rep * 256 + tid;
            float s = attb;
            #pragma unroll
            for (int k = 0; k < WIN_; k++) s += sh_rt[k * (BT + 8) + j + k];
            sh_sc[j] = 1.0f / (1.0f + __expf(-s));
        }
    }
    __syncthreads();

    // max over wave's 128 tokens; lane owns cols [l15*8, l15*8+8)
    float mm[8];
    #pragma unroll
    for (int c = 0; c < 8; c++) mm[c] = -INFINITY;

    #pragma unroll
    for (int batch = 0; batch < 4; batch++) {
        uintx4 uB[8];
        if (batch < 3) {
            const int nstart = base_t + (batch + 1) * 32;
            #pragma unroll
            for (int j = 0; j < 8; j++) {
                int tok = nstart + j * 4 + grp;
                int v   = sh_x[tok + PAD_];
                uB[j]   = *(const uintx4*)(D + (size_t)v * E_ + l15 * 8);
            }
        }

        const int start = base_t + batch * 32;
        float sc8[8];
        #pragma unroll
        for (int j = 0; j < 8; j++) sc8[j] = sh_sc[start + j * 4 + grp];

        #pragma unroll
        for (int j = 0; j < 8; j++) {
            #pragma unroll
            for (int q = 0; q < 4; q++) {
                float lo = __uint_as_float(uA[j][q] << 16);
                float hi = __uint_as_float(uA[j][q] & 0xFFFF0000u);
                mm[q * 2]     = fmaxf(mm[q * 2],     sc8[j] * lo);
                mm[q * 2 + 1] = fmaxf(mm[q * 2 + 1], sc8[j] * hi);
            }
        }

        #pragma unroll
        for (int j = 0; j < 8; j++) uA[j] = uB[j];
    }

    // fold across the 4 token-groups (lanes sharing l15)
    #pragma unroll
    for (int c = 0; c < 8; c++) {
        mm[c] = fmaxf(mm[c], __shfl_xor(mm[c], 16));
        mm[c] = fmaxf(mm[c], __shfl_xor(mm[c], 32));
    }
    if (lane < 16) {
        #pragma unroll
        for (int c = 0; c < 8; c++) sh_red[w * 128 + l15 * 8 + c] = mm[c];
    }
    __syncthreads();
    if (tid < 128) {
        float m = fmaxf(fmaxf(sh_red[0 * 128 + tid], sh_red[1 * 128 + tid]),
                        fmaxf(sh_red[2 * 128 + tid], sh_red[3 * 128 + tid]));
        atomicMaxFloat(&out[b * OC_ + tid], tanhf(m + cnn_b[tid]));
    }
}

// ============ fallback (small ws): monolithic fp32-gather version ============
__global__ void prep_small(const float* __restrict__ cnn_w, const float* __restrict__ att_w,
                           short* __restrict__ wsw, short* __restrict__ wsatt) {
    int i = blockIdx.x * 256 + threadIdx.x;
    if (i < OC_ * E_)  wsw[i]   = f2bf(cnn_w[i]);
    if (i < WIN_ * E_) wsatt[i] = f2bf(att_w[i]);
}

__launch_bounds__(256, 4)
__global__ void fallback_main(const int* __restrict__ x,
                              const float* __restrict__ emb,
                              const float* __restrict__ att_b_p,
                              const short* __restrict__ wsw,
                              const short* __restrict__ wsatt,
                              const float* __restrict__ cnn_b,
                              float* __restrict__ out) {
    __shared__ short sh_a[ROWS * ASTR];
    __shared__ short sh_att[16 * ASTR];
    __shared__ float sh_r[ROWS * 8];
    __shared__ float sh_score[TT];
    __shared__ int   sh_idx[8 * ROWS];

    const int tid  = threadIdx.x;
    const int lane = tid & 63;
    const int w    = tid >> 6;
    const int b    = blockIdx.y;
    const int t0   = blockIdx.x * (8 * TT);
    const int l15  = lane & 15;
    const int quad = lane >> 4;
    const int rbase = tid >> 4;
    const int c     = tid & 15;

    for (int i = tid; i < 8 * ROWS; i += 256) {
        int tile = i / ROWS, row = i - tile * ROWS;
        int t = t0 + tile * TT + row - PAD_;
        sh_idx[i] = (row < REAL_ROWS && t >= 0 && t < T_) ? x[b * T_ + t] : -1;
    }
    {
        int o = tid >> 4, cc = tid & 15;
        short8 v = (short8){0,0,0,0,0,0,0,0};
        if (o < WIN_) v = *(const short8*)(wsatt + o * E_ + cc * 8);
        *(short8*)(&sh_att[o * ASTR + cc * 8]) = v;
    }
    short8 Bf[2][4];
    #pragma unroll
    for (int j = 0; j < 2; j++)
        #pragma unroll
        for (int ks = 0; ks < 4; ks++)
            Bf[j][ks] = *(const short8*)(wsw + (size_t)(w * 32 + j * 16 + l15) * E_ + ks * 32 + quad * 8);
    __syncthreads();

    short8 g[5];
    #pragma unroll
    for (int k = 0; k < 5; k++) {
        int idx = sh_idx[rbase + 16 * k];
        short8 v = (short8){0,0,0,0,0,0,0,0};
        if (idx >= 0) {
            const float4* p = (const float4*)(emb + (size_t)idx * E_ + c * 8);
            float4 p0 = p[0], p1 = p[1];
            v = (short8){ f2bf(p0.x), f2bf(p0.y), f2bf(p0.z), f2bf(p0.w),
                          f2bf(p1.x), f2bf(p1.y), f2bf(p1.z), f2bf(p1.w) };
        }
        g[k] = v;
    }
    #pragma unroll
    for (int k = 0; k < 5; k++)
        *(short8*)(&sh_a[(rbase + 16 * k) * ASTR + c * 8]) = g[k];
    __syncthreads();

    const float attb = att_b_p[0];
    float mm[2] = { -INFINITY, -INFINITY };

    for (int it = 0; it < 8; it++) {
        for (int mt = w; mt < 5; mt += 4) {
            floatx4 acc = (floatx4){0.f, 0.f, 0.f, 0.f};
            #pragma unroll
            for (int ks = 0; ks < 4; ks++) {
                short8 a  = *(const short8*)(&sh_a[(mt * 16 + l15) * ASTR + ks * 32 + quad * 8]);
                short8 bs = *(const short8*)(&sh_att[l15 * ASTR + ks * 32 + quad * 8]);
                acc = __builtin_amdgcn_mfma_f32_16x16x32_bf16(a, bs, acc, 0, 0, 0);
            }
            if (l15 < 8) {
                #pragma unroll
                for (int r = 0; r < 4; r++)
                    sh_r[(mt * 16 + quad * 4 + r) * 8 + l15] = acc[r];
            }
        }
        __syncthreads();

        if (it + 1 < 8) {
            const int* idxp = &sh_idx[(it + 1) * ROWS];
            #pragma unroll
            for (int k = 0; k < 5; k++) {
                int idx = idxp[rbase + 16 * k];
                short8 v = (short8){0,0,0,0,0,0,0,0};
                if (idx >= 0) {
                    const float4* p = (const float4*)(emb + (size_t)idx * E_ + c * 8);
                    float4 p0 = p[0], p1 = p[1];
                    v = (short8){ f2bf(p0.x), f2bf(p0.y), f2bf(p0.z), f2bf(p0.w),
                                  f2bf(p1.x), f2bf(p1.y), f2bf(p1.z), f2bf(p1.w) };
                }
                g[k] = v;
            }
        }

        if (tid < TT) {
            float s = attb;
            #pragma unroll
            for (int k = 0; k < WIN_; k++) s += sh_r[(tid + k) * 8 + k];
            sh_score[tid] = 1.0f / (1.0f + __expf(-s));
        }

        floatx4 acc[4][2];
        #pragma unroll
        for (int i = 0; i < 4; i++)
            #pragma unroll
            for (int j = 0; j < 2; j++) acc[i][j] = (floatx4){0.f, 0.f, 0.f, 0.f};
        #pragma unroll
        for (int ks = 0; ks < 4; ks++) {
            int ko = ks * 32 + quad * 8;
            #pragma unroll
            for (int i = 0; i < 4; i++) {
                short8 ai = *(const short8*)(&sh_a[(PAD_ + i * 16 + l15) * ASTR + ko]);
                acc[i][0] = __builtin_amdgcn_mfma_f32_16x16x32_bf16(ai, Bf[0][ks], acc[i][0], 0, 0, 0);
                acc[i][1] = __builtin_amdgcn_mfma_f32_16x16x32_bf16(ai, Bf[1][ks], acc[i][1], 0, 0, 0);
            }
        }
        __syncthreads();

        #pragma unroll
        for (int i = 0; i < 4; i++) {
            #pragma unroll
            for (int r = 0; r < 4; r++) {
                float sc = sh_score[i * 16 + quad * 4 + r];
                mm[0] = fmaxf(mm[0], sc * acc[i][0][r]);
                mm[1] = fmaxf(mm[1], sc * acc[i][1][r]);
            }
        }

        if (it + 1 < 8) {
            #pragma unroll
            for (int k = 0; k < 5; k++)
                *(short8*)(&sh_a[(rbase + 16 * k) * ASTR + c * 8]) = g[k];
            __syncthreads();
        }
    }

    #pragma unroll
    for (int j = 0; j < 2; j++) {
        float m = mm[j];
        m = fmaxf(m, __shfl_xor(m, 16));
        m = fmaxf(m, __shfl_xor(m, 32));
        if (lane < 16) {
            int o = w * 32 + j * 16 + lane;
            atomicMaxFloat(&out[b * OC_ + o], tanhf(m + cnn_b[o]));
        }
    }
}

extern "C" void kernel_launch(void* const* d_in, const int* in_sizes, int n_in,
                              void* d_out, int out_size, void* d_ws, size_t ws_size,
                              hipStream_t stream) {
    const int*   x     = (const int*)d_in[0];
    const float* emb   = (const float*)d_in[1];
    const float* att_w = (const float*)d_in[2];
    const float* att_b = (const float*)d_in[3];
    const float* cnn_w = (const float*)d_in[4];
    const float* cnn_b = (const float*)d_in[5];
    float* out = (float*)d_out;

    const size_t d_elems = (size_t)VOCAB1 * E_;     // bf16 count
    const size_t r_elems = (size_t)VOCAB1 * 8;      // fp32 count
    const size_t need = d_elems * 2 + r_elems * 4 + 128;

    if (ws_size >= need) {
        short*    Dt  = (short*)d_ws;
        float*    rt  = (float*)(Dt + d_elems);
        unsigned* bar = (unsigned*)((char*)d_ws + d_elems * 2 + r_elems * 4);
        hipMemsetAsync(bar, 0, 64, stream);
        fused_all<<<NBLK, 256, 0, stream>>>(x, emb, cnn_w, att_w, att_b, cnn_b, Dt, rt, bar, out);
    } else {
        hipMemsetAsync(d_out, 0xFF, (size_t)B_ * OC_ * sizeof(float), stream);
        short* ws_w   = (short*)d_ws;
        short* ws_att = ws_w + OC_ * E_;
        prep_small<<<16, 256, 0, stream>>>(cnn_w, att_w, ws_w, ws_att);
        dim3 grid(T_ / (8 * TT), B_);
        fallback_main<<<grid, 256, 0, stream>>>(x, emb, att_b, ws_w, ws_att, cnn_b, out);
    }
}

// Round 3
// 112.712 us; speedup vs baseline: 2.0885x; 2.0885x over previous
//
#include <hip/hip_runtime.h>
#include <hip/hip_bf16.h>
#include <math.h>

// B,T,E,WIN,OC,VOCAB = 256,2048,128,5,128,50000
#define B_   256
#define T_   2048
#define E_   128
#define WIN_ 5
#define PAD_ 2
#define OC_  128
#define VOCAB_MAX 50000
#define VOCAB1 50001
#define TT   64
#define REAL_ROWS (TT + WIN_ - 1)
#define ROWS 80
#define ASTR 136                  // LDS row stride (bf16): 272B -> 2-way alias = free
#define VROWS 64                  // vocab rows per build_tables block
#define BT   256                  // tokens per score_max block (halved: 2048 blocks -> 8/CU)

typedef __attribute__((ext_vector_type(8))) short short8;
typedef __attribute__((ext_vector_type(4))) float floatx4;
typedef __attribute__((ext_vector_type(4))) unsigned uintx4;

static __device__ __forceinline__ short f2bf(float f) {
    union { __hip_bfloat16 h; short s; } u;
    u.h = __float2bfloat16(f);
    return u.s;
}

__device__ __forceinline__ void atomicMaxFloat(float* addr, float v) {
    // requires init to -inf: works on both sign paths
    if (v >= 0.0f) atomicMax((int*)addr, __float_as_int(v));
    else           atomicMin((unsigned int*)addr, __float_as_uint(v));
}

// ============ P1: vocab-level tables ============
// D[v][o] = <emb[v], cnn_w[o]>  (bf16)
// r[v][k] = <emb[v], att_w[k]>  (fp32, k<5; slots 5..7 zero)
// Also initializes out[] to -inf (blocks 0..127).
__launch_bounds__(256, 4)
__global__ void build_tables(const float* __restrict__ emb,
                             const float* __restrict__ cnn_w,
                             const float* __restrict__ att_w,
                             short* __restrict__ D,
                             float* __restrict__ r,
                             float* __restrict__ out) {
    __shared__ __align__(16) short sh_a[VROWS * ASTR];   // 17408 B  (emb tile, bf16)
    __shared__ __align__(16) short sh_d[VROWS * ASTR];   // 17408 B  (D tile staging)

    const int tid  = threadIdx.x;
    const int lane = tid & 63;
    const int w    = tid >> 6;
    const int l15  = lane & 15;
    const int quad = lane >> 4;
    const int v0   = blockIdx.x * VROWS;

    if (blockIdx.x < (B_ * OC_) / 256)
        out[blockIdx.x * 256 + tid] = -INFINITY;

    // stage 64 vocab rows fp32 -> bf16 (coalesced; clamp OOB rows)
    #pragma unroll
    for (int t = 0; t < 8; t++) {
        int i   = t * 256 + tid;
        int row = i >> 5, c4 = i & 31;
        int vr  = v0 + row; if (vr > VOCAB_MAX) vr = VOCAB_MAX;
        float4 v = *(const float4*)(emb + (size_t)vr * E_ + c4 * 4);
        short4 o; o.x = f2bf(v.x); o.y = f2bf(v.y); o.z = f2bf(v.z); o.w = f2bf(v.w);
        *(short4*)(&sh_a[row * ASTR + c4 * 4]) = o;
    }

    // B fragments (cnn_w fp32 -> bf16): wave w -> cols [w*32, w*32+32)
    short8 Bf[2][4];
    #pragma unroll
    for (int j = 0; j < 2; j++)
        #pragma unroll
        for (int ks = 0; ks < 4; ks++) {
            const float4* p = (const float4*)(cnn_w + (size_t)(w * 32 + j * 16 + l15) * E_ + ks * 32 + quad * 8);
            float4 p0 = p[0], p1 = p[1];
            Bf[j][ks] = (short8){ f2bf(p0.x), f2bf(p0.y), f2bf(p0.z), f2bf(p0.w),
                                  f2bf(p1.x), f2bf(p1.y), f2bf(p1.z), f2bf(p1.w) };
        }

    // att-tap fragments (taps >= WIN_ are zero)
    short8 Ba[4];
    #pragma unroll
    for (int ks = 0; ks < 4; ks++) {
        short8 v = (short8){0,0,0,0,0,0,0,0};
        if (l15 < WIN_) {
            const float4* p = (const float4*)(att_w + (size_t)l15 * E_ + ks * 32 + quad * 8);
            float4 p0 = p[0], p1 = p[1];
            v = (short8){ f2bf(p0.x), f2bf(p0.y), f2bf(p0.z), f2bf(p0.w),
                          f2bf(p1.x), f2bf(p1.y), f2bf(p1.z), f2bf(p1.w) };
        }
        Ba[ks] = v;
    }
    __syncthreads();

    // D tiles: 4 m-tiles x 2 n-tiles per wave -> stage into sh_d
    #pragma unroll
    for (int mt = 0; mt < 4; mt++) {
        short8 a[4];
        #pragma unroll
        for (int ks = 0; ks < 4; ks++)
            a[ks] = *(const short8*)(&sh_a[(mt * 16 + l15) * ASTR + ks * 32 + quad * 8]);
        #pragma unroll
        for (int j = 0; j < 2; j++) {
            floatx4 acc = (floatx4){0.f, 0.f, 0.f, 0.f};
            #pragma unroll
            for (int ks = 0; ks < 4; ks++)
                acc = __builtin_amdgcn_mfma_f32_16x16x32_bf16(a[ks], Bf[j][ks], acc, 0, 0, 0);
            #pragma unroll
            for (int rr = 0; rr < 4; rr++)
                sh_d[(mt * 16 + quad * 4 + rr) * ASTR + w * 32 + j * 16 + l15] = f2bf(acc[rr]);
        }
    }

    // r tile: wave w handles m-tile w (small: scalar stores)
    {
        short8 a[4];
        #pragma unroll
        for (int ks = 0; ks < 4; ks++)
            a[ks] = *(const short8*)(&sh_a[(w * 16 + l15) * ASTR + ks * 32 + quad * 8]);
        floatx4 acc = (floatx4){0.f, 0.f, 0.f, 0.f};
        #pragma unroll
        for (int ks = 0; ks < 4; ks++)
            acc = __builtin_amdgcn_mfma_f32_16x16x32_bf16(a[ks], Ba[ks], acc, 0, 0, 0);
        if (l15 < 8) {
            #pragma unroll
            for (int rr = 0; rr < 4; rr++) {
                int v = v0 + w * 16 + quad * 4 + rr;
                if (v <= VOCAB_MAX) r[(size_t)v * 8 + l15] = acc[rr];
            }
        }
    }
    __syncthreads();

    // coalesced D store: thread covers 4 x 16-B chunks (dwordx4, fully coalesced)
    #pragma unroll
    for (int st = 0; st < 4; st++) {
        int i   = st * 256 + tid;
        int row = i >> 4, c = i & 15;     // 16 chunks of 16 B per 256-B row
        int v   = v0 + row;
        if (v <= VOCAB_MAX)
            *(short8*)(D + (size_t)v * E_ + c * 8) =
                *(const short8*)(&sh_d[row * ASTR + c * 8]);
    }
}

// ============ P2: streaming score + max (256 tokens/block, 2048 blocks) ============
// Halved tile vs v1: 8 blocks/CU worth of grid (was grid-limited at 4/CU), shorter
// serial phase chain per block, LDS 9.4 KB. (256,6) cap: measured usage ~60 VGPR.
__launch_bounds__(256, 6)
__global__ void score_max(const int* __restrict__ x,
                          const short* __restrict__ D,
                          const float* __restrict__ r,
                          const float* __restrict__ att_b_p,
                          const float* __restrict__ cnn_b,
                          float* __restrict__ out) {
    __shared__ int   sh_x[BT + 4];          // 1040 B
    __shared__ float sh_rt[WIN_][BT + 8];   // 5280 B (SoA: conflict-free)
    __shared__ float sh_sc[BT];             // 1024 B
    __shared__ float sh_red[4][128];        // 2048 B  -> ~9.4 KB

    const int tid  = threadIdx.x;
    const int lane = tid & 63;
    const int w    = tid >> 6;
    const int b    = blockIdx.y;
    const int t0   = blockIdx.x * BT;
    const int l15  = lane & 15;
    const int grp  = lane >> 4;

    // phase 1: token indices + r-row gather into SoA LDS (merged)
    for (int i = tid; i < BT + 4; i += 256) {
        int t = t0 + i - PAD_;
        int v = (t >= 0 && t < T_) ? x[b * T_ + t] : -1;
        sh_x[i] = v;
        float4 r03 = make_float4(0.f, 0.f, 0.f, 0.f);
        float  r4  = 0.f;
        if (v >= 0) {
            r03 = *(const float4*)(r + (size_t)v * 8);
            r4  = r[(size_t)v * 8 + 4];
        }
        sh_rt[0][i] = r03.x; sh_rt[1][i] = r03.y; sh_rt[2][i] = r03.z;
        sh_rt[3][i] = r03.w; sh_rt[4][i] = r4;
    }
    __syncthreads();

    const int base_t = w * 64;              // wave owns 64 tokens

    // prefetch batch 0 D-gathers (addresses only need sh_x) — overlaps score phase
    uintx4 uA[8];
    #pragma unroll
    for (int j = 0; j < 8; j++) {
        int tok = base_t + j * 4 + grp;
        int v   = sh_x[tok + PAD_];
        uA[j]   = *(const uintx4*)(D + (size_t)v * E_ + l15 * 8);
    }

    // phase 2: window-sum + sigmoid (LDS only)
    {
        const float attb = att_b_p[0];
        float s = attb;
        #pragma unroll
        for (int k = 0; k < WIN_; k++) s += sh_rt[k][tid + k];
        sh_sc[tid] = 1.0f / (1.0f + __expf(-s));
    }
    __syncthreads();

    // phase 3: max over wave's 64 tokens; lane owns cols [l15*8, l15*8+8)
    float mm[8];
    #pragma unroll
    for (int c = 0; c < 8; c++) mm[c] = -INFINITY;

    #pragma unroll
    for (int batch = 0; batch < 2; batch++) {
        uintx4 uB[8];
        if (batch < 1) {
            const int nstart = base_t + 32;
            #pragma unroll
            for (int j = 0; j < 8; j++) {
                int tok = nstart + j * 4 + grp;
                int v   = sh_x[tok + PAD_];
                uB[j]   = *(const uintx4*)(D + (size_t)v * E_ + l15 * 8);
            }
        }

        const int start = base_t + batch * 32;
        float sc8[8];
        #pragma unroll
        for (int j = 0; j < 8; j++) sc8[j] = sh_sc[start + j * 4 + grp];

        #pragma unroll
        for (int j = 0; j < 8; j++) {
            #pragma unroll
            for (int q = 0; q < 4; q++) {
                float lo = __uint_as_float(uA[j][q] << 16);
                float hi = __uint_as_float(uA[j][q] & 0xFFFF0000u);
                mm[q * 2]     = fmaxf(mm[q * 2],     sc8[j] * lo);
                mm[q * 2 + 1] = fmaxf(mm[q * 2 + 1], sc8[j] * hi);
            }
        }

        #pragma unroll
        for (int j = 0; j < 8; j++) uA[j] = uB[j];   // renamed away by unroll
    }

    // fold across the 4 token-groups (lanes sharing l15)
    #pragma unroll
    for (int c = 0; c < 8; c++) {
        mm[c] = fmaxf(mm[c], __shfl_xor(mm[c], 16));
        mm[c] = fmaxf(mm[c], __shfl_xor(mm[c], 32));
    }
    if (lane < 16) {
        #pragma unroll
        for (int c = 0; c < 8; c++) sh_red[w][l15 * 8 + c] = mm[c];
    }
    __syncthreads();
    if (tid < 128) {
        float m = fmaxf(fmaxf(sh_red[0][tid], sh_red[1][tid]),
                        fmaxf(sh_red[2][tid], sh_red[3][tid]));
        atomicMaxFloat(&out[b * OC_ + tid], tanhf(m + cnn_b[tid]));
    }
}

// ============ fallback (small ws): monolithic fp32-gather version ============
__global__ void prep_small(const float* __restrict__ cnn_w, const float* __restrict__ att_w,
                           short* __restrict__ wsw, short* __restrict__ wsatt) {
    int i = blockIdx.x * 256 + threadIdx.x;
    if (i < OC_ * E_)  wsw[i]   = f2bf(cnn_w[i]);
    if (i < WIN_ * E_) wsatt[i] = f2bf(att_w[i]);
}

__launch_bounds__(256, 4)
__global__ void fallback_main(const int* __restrict__ x,
                              const float* __restrict__ emb,
                              const float* __restrict__ att_b_p,
                              const short* __restrict__ wsw,
                              const short* __restrict__ wsatt,
                              const float* __restrict__ cnn_b,
                              float* __restrict__ out) {
    __shared__ short sh_a[ROWS * ASTR];
    __shared__ short sh_att[16 * ASTR];
    __shared__ float sh_r[ROWS * 8];
    __shared__ float sh_score[TT];
    __shared__ int   sh_idx[8 * ROWS];

    const int tid  = threadIdx.x;
    const int lane = tid & 63;
    const int w    = tid >> 6;
    const int b    = blockIdx.y;
    const int t0   = blockIdx.x * (8 * TT);
    const int l15  = lane & 15;
    const int quad = lane >> 4;
    const int rbase = tid >> 4;
    const int c     = tid & 15;

    for (int i = tid; i < 8 * ROWS; i += 256) {
        int tile = i / ROWS, row = i - tile * ROWS;
        int t = t0 + tile * TT + row - PAD_;
        sh_idx[i] = (row < REAL_ROWS && t >= 0 && t < T_) ? x[b * T_ + t] : -1;
    }
    {
        int o = tid >> 4, cc = tid & 15;
        short8 v = (short8){0,0,0,0,0,0,0,0};
        if (o < WIN_) v = *(const short8*)(wsatt + o * E_ + cc * 8);
        *(short8*)(&sh_att[o * ASTR + cc * 8]) = v;
    }
    short8 Bf[2][4];
    #pragma unroll
    for (int j = 0; j < 2; j++)
        #pragma unroll
        for (int ks = 0; ks < 4; ks++)
            Bf[j][ks] = *(const short8*)(wsw + (size_t)(w * 32 + j * 16 + l15) * E_ + ks * 32 + quad * 8);
    __syncthreads();

    short8 g[5];
    #pragma unroll
    for (int k = 0; k < 5; k++) {
        int idx = sh_idx[rbase + 16 * k];
        short8 v = (short8){0,0,0,0,0,0,0,0};
        if (idx >= 0) {
            const float4* p = (const float4*)(emb + (size_t)idx * E_ + c * 8);
            float4 p0 = p[0], p1 = p[1];
            v = (short8){ f2bf(p0.x), f2bf(p0.y), f2bf(p0.z), f2bf(p0.w),
                          f2bf(p1.x), f2bf(p1.y), f2bf(p1.z), f2bf(p1.w) };
        }
        g[k] = v;
    }
    #pragma unroll
    for (int k = 0; k < 5; k++)
        *(short8*)(&sh_a[(rbase + 16 * k) * ASTR + c * 8]) = g[k];
    __syncthreads();

    const float attb = att_b_p[0];
    float mm[2] = { -INFINITY, -INFINITY };

    for (int it = 0; it < 8; it++) {
        for (int mt = w; mt < 5; mt += 4) {
            floatx4 acc = (floatx4){0.f, 0.f, 0.f, 0.f};
            #pragma unroll
            for (int ks = 0; ks < 4; ks++) {
                short8 a  = *(const short8*)(&sh_a[(mt * 16 + l15) * ASTR + ks * 32 + quad * 8]);
                short8 bs = *(const short8*)(&sh_att[l15 * ASTR + ks * 32 + quad * 8]);
                acc = __builtin_amdgcn_mfma_f32_16x16x32_bf16(a, bs, acc, 0, 0, 0);
            }
            if (l15 < 8) {
                #pragma unroll
                for (int r = 0; r < 4; r++)
                    sh_r[(mt * 16 + quad * 4 + r) * 8 + l15] = acc[r];
            }
        }
        __syncthreads();

        if (it + 1 < 8) {
            const int* idxp = &sh_idx[(it + 1) * ROWS];
            #pragma unroll
            for (int k = 0; k < 5; k++) {
                int idx = idxp[rbase + 16 * k];
                short8 v = (short8){0,0,0,0,0,0,0,0};
                if (idx >= 0) {
                    const float4* p = (const float4*)(emb + (size_t)idx * E_ + c * 8);
                    float4 p0 = p[0], p1 = p[1];
                    v = (short8){ f2bf(p0.x), f2bf(p0.y), f2bf(p0.z), f2bf(p0.w),
                                  f2bf(p1.x), f2bf(p1.y), f2bf(p1.z), f2bf(p1.w) };
                }
                g[k] = v;
            }
        }

        if (tid < TT) {
            float s = attb;
            #pragma unroll
            for (int k = 0; k < WIN_; k++) s += sh_r[(tid + k) * 8 + k];
            sh_score[tid] = 1.0f / (1.0f + __expf(-s));
        }

        floatx4 acc[4][2];
        #pragma unroll
        for (int i = 0; i < 4; i++)
            #pragma unroll
            for (int j = 0; j < 2; j++) acc[i][j] = (floatx4){0.f, 0.f, 0.f, 0.f};
        #pragma unroll
        for (int ks = 0; ks < 4; ks++) {
            int ko = ks * 32 + quad * 8;
            #pragma unroll
            for (int i = 0; i < 4; i++) {
                short8 ai = *(const short8*)(&sh_a[(PAD_ + i * 16 + l15) * ASTR + ko]);
                acc[i][0] = __builtin_amdgcn_mfma_f32_16x16x32_bf16(ai, Bf[0][ks], acc[i][0], 0, 0, 0);
                acc[i][1] = __builtin_amdgcn_mfma_f32_16x16x32_bf16(ai, Bf[1][ks], acc[i][1], 0, 0, 0);
            }
        }
        __syncthreads();

        #pragma unroll
        for (int i = 0; i < 4; i++) {
            #pragma unroll
            for (int r = 0; r < 4; r++) {
                float sc = sh_score[i * 16 + quad * 4 + r];
                mm[0] = fmaxf(mm[0], sc * acc[i][0][r]);
                mm[1] = fmaxf(mm[1], sc * acc[i][1][r]);
            }
        }

        if (it + 1 < 8) {
            #pragma unroll
            for (int k = 0; k < 5; k++)
                *(short8*)(&sh_a[(rbase + 16 * k) * ASTR + c * 8]) = g[k];
            __syncthreads();
        }
    }

    #pragma unroll
    for (int j = 0; j < 2; j++) {
        float m = mm[j];
        m = fmaxf(m, __shfl_xor(m, 16));
        m = fmaxf(m, __shfl_xor(m, 32));
        if (lane < 16) {
            int o = w * 32 + j * 16 + lane;
            atomicMaxFloat(&out[b * OC_ + o], tanhf(m + cnn_b[o]));
        }
    }
}

extern "C" void kernel_launch(void* const* d_in, const int* in_sizes, int n_in,
                              void* d_out, int out_size, void* d_ws, size_t ws_size,
                              hipStream_t stream) {
    const int*   x     = (const int*)d_in[0];
    const float* emb   = (const float*)d_in[1];
    const float* att_w = (const float*)d_in[2];
    const float* att_b = (const float*)d_in[3];
    const float* cnn_w = (const float*)d_in[4];
    const float* cnn_b = (const float*)d_in[5];
    float* out = (float*)d_out;

    const size_t d_elems = (size_t)VOCAB1 * E_;     // bf16 count
    const size_t r_elems = (size_t)VOCAB1 * 8;      // fp32 count
    const size_t need = d_elems * 2 + r_elems * 4 + 64;

    if (ws_size >= need) {
        short* Dt = (short*)d_ws;
        float* rt = (float*)(Dt + d_elems);
        build_tables<<<(VOCAB1 + VROWS - 1) / VROWS, 256, 0, stream>>>(emb, cnn_w, att_w, Dt, rt, out);
        dim3 grid(T_ / BT, B_);                      // (8, 256) = 2048 blocks
        score_max<<<grid, 256, 0, stream>>>(x, Dt, rt, att_b, cnn_b, out);
    } else {
        hipMemsetAsync(d_out, 0xFF, (size_t)B_ * OC_ * sizeof(float), stream);
        short* ws_w   = (short*)d_ws;
        short* ws_att = ws_w + OC_ * E_;
        prep_small<<<16, 256, 0, stream>>>(cnn_w, att_w, ws_w, ws_att);
        dim3 grid(T_ / (8 * TT), B_);
        fallback_main<<<grid, 256, 0, stream>>>(x, emb, att_b, ws_w, ws_att, cnn_b, out);
    }
}

// Round 4
// 106.407 us; speedup vs baseline: 2.2122x; 1.0593x over previous
//
#include <hip/hip_runtime.h>
#include <hip/hip_bf16.h>
#include <math.h>

// B,T,E,WIN,OC,VOCAB = 256,2048,128,5,128,50000
#define B_   256
#define T_   2048
#define E_   128
#define WIN_ 5
#define PAD_ 2
#define OC_  128
#define VOCAB_MAX 50000
#define VOCAB1 50001
#define TT   64
#define REAL_ROWS (TT + WIN_ - 1)
#define ROWS 80
#define ASTR 136                  // LDS row stride (bf16): 272B -> 2-way alias = free
#define DSTR 132                  // fp32 D-tile stride (floats): 2-way alias max = free
#define VROWS 64                  // vocab rows per build_tables block
#define BT   256                  // tokens per score_max block

typedef __attribute__((ext_vector_type(8))) short short8;
typedef __attribute__((ext_vector_type(4))) float floatx4;
typedef __attribute__((ext_vector_type(4))) unsigned uintx4;

static __device__ __forceinline__ short f2bf(float f) {
    union { __hip_bfloat16 h; short s; } u;
    u.h = __float2bfloat16(f);
    return u.s;
}

__device__ __forceinline__ void atomicMaxFloat(float* addr, float v) {
    // requires init to -inf: works on both sign paths
    if (v >= 0.0f) atomicMax((int*)addr, __float_as_int(v));
    else           atomicMin((unsigned int*)addr, __float_as_uint(v));
}

// ============ P1: vocab-level tables (int8 D + per-row scale) ============
// D8[v][o] = round(<emb[v],cnn_w[o]> * 127/rowmax)  (int8)
// rs[v]    = rowmax/127                              (f32)
// r[v][k]  = <emb[v], att_w[k]>                      (f32, k<5)
// Also initializes out[] to -inf (blocks 0..127).
__launch_bounds__(256, 3)
__global__ void build_tables(const float* __restrict__ emb,
                             const float* __restrict__ cnn_w,
                             const float* __restrict__ att_w,
                             unsigned char* __restrict__ D8,
                             float* __restrict__ r,
                             float* __restrict__ rs,
                             float* __restrict__ out) {
    __shared__ __align__(16) short sh_a[VROWS * ASTR];    // 17408 B (emb tile, bf16)
    __shared__ __align__(16) float sh_df[VROWS * DSTR];   // 33792 B (D tile, fp32)
    __shared__ float sh_inv[VROWS];                       // 256 B   -> ~51.5 KB, 3 blk/CU

    const int tid  = threadIdx.x;
    const int lane = tid & 63;
    const int w    = tid >> 6;
    const int l15  = lane & 15;
    const int quad = lane >> 4;
    const int v0   = blockIdx.x * VROWS;

    if (blockIdx.x < (B_ * OC_) / 256)
        out[blockIdx.x * 256 + tid] = -INFINITY;

    // stage 64 vocab rows fp32 -> bf16 (coalesced; clamp OOB rows)
    #pragma unroll
    for (int t = 0; t < 8; t++) {
        int i   = t * 256 + tid;
        int row = i >> 5, c4 = i & 31;
        int vr  = v0 + row; if (vr > VOCAB_MAX) vr = VOCAB_MAX;
        float4 v = *(const float4*)(emb + (size_t)vr * E_ + c4 * 4);
        short4 o; o.x = f2bf(v.x); o.y = f2bf(v.y); o.z = f2bf(v.z); o.w = f2bf(v.w);
        *(short4*)(&sh_a[row * ASTR + c4 * 4]) = o;
    }

    // B fragments (cnn_w fp32 -> bf16): wave w -> cols [w*32, w*32+32)
    short8 Bf[2][4];
    #pragma unroll
    for (int j = 0; j < 2; j++)
        #pragma unroll
        for (int ks = 0; ks < 4; ks++) {
            const float4* p = (const float4*)(cnn_w + (size_t)(w * 32 + j * 16 + l15) * E_ + ks * 32 + quad * 8);
            float4 p0 = p[0], p1 = p[1];
            Bf[j][ks] = (short8){ f2bf(p0.x), f2bf(p0.y), f2bf(p0.z), f2bf(p0.w),
                                  f2bf(p1.x), f2bf(p1.y), f2bf(p1.z), f2bf(p1.w) };
        }

    // att-tap fragments (taps >= WIN_ are zero)
    short8 Ba[4];
    #pragma unroll
    for (int ks = 0; ks < 4; ks++) {
        short8 v = (short8){0,0,0,0,0,0,0,0};
        if (l15 < WIN_) {
            const float4* p = (const float4*)(att_w + (size_t)l15 * E_ + ks * 32 + quad * 8);
            float4 p0 = p[0], p1 = p[1];
            v = (short8){ f2bf(p0.x), f2bf(p0.y), f2bf(p0.z), f2bf(p0.w),
                          f2bf(p1.x), f2bf(p1.y), f2bf(p1.z), f2bf(p1.w) };
        }
        Ba[ks] = v;
    }
    __syncthreads();

    // D tiles: 4 m-tiles x 2 n-tiles per wave -> fp32 staging (no bf16 re-round)
    #pragma unroll
    for (int mt = 0; mt < 4; mt++) {
        short8 a[4];
        #pragma unroll
        for (int ks = 0; ks < 4; ks++)
            a[ks] = *(const short8*)(&sh_a[(mt * 16 + l15) * ASTR + ks * 32 + quad * 8]);
        #pragma unroll
        for (int j = 0; j < 2; j++) {
            floatx4 acc = (floatx4){0.f, 0.f, 0.f, 0.f};
            #pragma unroll
            for (int ks = 0; ks < 4; ks++)
                acc = __builtin_amdgcn_mfma_f32_16x16x32_bf16(a[ks], Bf[j][ks], acc, 0, 0, 0);
            #pragma unroll
            for (int rr = 0; rr < 4; rr++)
                sh_df[(mt * 16 + quad * 4 + rr) * DSTR + w * 32 + j * 16 + l15] = acc[rr];
        }
    }

    // r tile: wave w handles m-tile w
    {
        short8 a[4];
        #pragma unroll
        for (int ks = 0; ks < 4; ks++)
            a[ks] = *(const short8*)(&sh_a[(w * 16 + l15) * ASTR + ks * 32 + quad * 8]);
        floatx4 acc = (floatx4){0.f, 0.f, 0.f, 0.f};
        #pragma unroll
        for (int ks = 0; ks < 4; ks++)
            acc = __builtin_amdgcn_mfma_f32_16x16x32_bf16(a[ks], Ba[ks], acc, 0, 0, 0);
        if (l15 < 8) {
            #pragma unroll
            for (int rr = 0; rr < 4; rr++) {
                int v = v0 + w * 16 + quad * 4 + rr;
                if (v <= VOCAB_MAX) r[(size_t)v * 8 + l15] = acc[rr];
            }
        }
    }
    __syncthreads();

    // row-max |D| (4 threads/row; partners are adjacent lanes -> shfl fold)
    {
        int row = tid >> 2, seg = tid & 3;
        const float4* p = (const float4*)(&sh_df[row * DSTR + seg * 32]);
        float m = 0.f;
        #pragma unroll
        for (int k = 0; k < 8; k++) {
            float4 v = p[k];
            m = fmaxf(m, fmaxf(fmaxf(fabsf(v.x), fabsf(v.y)), fmaxf(fabsf(v.z), fabsf(v.w))));
        }
        m = fmaxf(m, __shfl_xor(m, 1));
        m = fmaxf(m, __shfl_xor(m, 2));
        if (seg == 0) {
            sh_inv[row] = (m > 0.f) ? 127.f / m : 0.f;
            int v = v0 + row;
            if (v <= VOCAB_MAX) rs[v] = m * (1.f / 127.f);
        }
    }
    __syncthreads();

    // quantize + coalesced int8 store: 2 iters x 256 threads x 16 B chunks
    #pragma unroll
    for (int st = 0; st < 2; st++) {
        int idx = st * 256 + tid;
        int row = idx >> 3, c8 = idx & 7;       // 8 chunks of 16 int8 per 128-B row
        float inv = sh_inv[row];
        const float* p = &sh_df[row * DSTR + c8 * 16];
        uintx4 outw;
        #pragma unroll
        for (int q = 0; q < 4; q++) {
            unsigned dw = 0;
            #pragma unroll
            for (int k = 0; k < 4; k++) {
                int qi = (int)rintf(p[q * 4 + k] * inv);
                dw |= ((unsigned)(qi & 0xFF)) << (k * 8);
            }
            outw[q] = dw;
        }
        int v = v0 + row;
        if (v <= VOCAB_MAX)
            *(uintx4*)(D8 + (size_t)v * OC_ + c8 * 16) = outw;
    }
}

// ============ P2: streaming score + max (256 tokens/block, 2048 blocks) ============
// int8 D rows: 128 B/token (half of bf16), 8 tokens per gather instruction,
// 8 loads in flight per lane issued before the score phase.
__launch_bounds__(256, 4)
__global__ void score_max(const int* __restrict__ x,
                          const unsigned char* __restrict__ D8,
                          const float* __restrict__ r,
                          const float* __restrict__ rs,
                          const float* __restrict__ att_b_p,
                          const float* __restrict__ cnn_b,
                          float* __restrict__ out) {
    __shared__ int   sh_x[BT + 4];          // 1040 B
    __shared__ float sh_rs[BT + 4];         // 1040 B (per-token row scale)
    __shared__ float sh_rt[WIN_][BT + 8];   // 5280 B (SoA: conflict-free)
    __shared__ float sh_sc[BT];             // 1024 B (sigmoid * rowscale)
    __shared__ float sh_red[4][128];        // 2048 B -> ~10.4 KB

    const int tid  = threadIdx.x;
    const int lane = tid & 63;
    const int w    = tid >> 6;
    const int b    = blockIdx.y;
    const int t0   = blockIdx.x * BT;
    const int l7   = lane & 7;
    const int grp8 = lane >> 3;

    // phase 1: token indices + r-row + rowscale gather into LDS
    for (int i = tid; i < BT + 4; i += 256) {
        int t = t0 + i - PAD_;
        int v = (t >= 0 && t < T_) ? x[b * T_ + t] : -1;
        sh_x[i] = v;
        float4 r03 = make_float4(0.f, 0.f, 0.f, 0.f);
        float  r4  = 0.f, rsv = 0.f;
        if (v >= 0) {
            r03 = *(const float4*)(r + (size_t)v * 8);
            r4  = r[(size_t)v * 8 + 4];
            rsv = rs[v];
        }
        sh_rt[0][i] = r03.x; sh_rt[1][i] = r03.y; sh_rt[2][i] = r03.z;
        sh_rt[3][i] = r03.w; sh_rt[4][i] = r4;
        sh_rs[i] = rsv;
    }
    __syncthreads();

    const int base_t = w * 64;              // wave owns 64 tokens

    // issue all 8 D8-gathers (wave's 64 tokens x 128 B) before the score phase
    uintx4 u[8];
    #pragma unroll
    for (int j = 0; j < 8; j++) {
        int tok = base_t + j * 8 + grp8;
        int v   = sh_x[tok + PAD_];
        u[j]    = *(const uintx4*)(D8 + (size_t)v * OC_ + l7 * 16);
    }

    // phase 2: window-sum + sigmoid, folded with rowscale (LDS only)
    {
        const float attb = att_b_p[0];
        float s = attb;
        #pragma unroll
        for (int k = 0; k < WIN_; k++) s += sh_rt[k][tid + k];
        sh_sc[tid] = sh_rs[tid + PAD_] / (1.0f + __expf(-s));
    }
    __syncthreads();

    // phase 3: max over wave's 64 tokens; lane owns cols [l7*16, l7*16+16)
    float mm[16];
    #pragma unroll
    for (int c = 0; c < 16; c++) mm[c] = -INFINITY;

    float sc8[8];
    #pragma unroll
    for (int j = 0; j < 8; j++) sc8[j] = sh_sc[base_t + j * 8 + grp8];

    #pragma unroll
    for (int j = 0; j < 8; j++) {
        #pragma unroll
        for (int q = 0; q < 4; q++) {
            unsigned dw = u[j][q];
            #pragma unroll
            for (int k = 0; k < 4; k++) {
                int val = ((int)dw << (24 - k * 8)) >> 24;   // sext int8
                mm[q * 4 + k] = fmaxf(mm[q * 4 + k], sc8[j] * (float)val);
            }
        }
    }

    // fold across the 8 token-groups (lanes sharing l7)
    #pragma unroll
    for (int c = 0; c < 16; c++) {
        mm[c] = fmaxf(mm[c], __shfl_xor(mm[c], 8));
        mm[c] = fmaxf(mm[c], __shfl_xor(mm[c], 16));
        mm[c] = fmaxf(mm[c], __shfl_xor(mm[c], 32));
    }
    if (grp8 == 0) {
        #pragma unroll
        for (int c = 0; c < 16; c++) sh_red[w][l7 * 16 + c] = mm[c];
    }
    __syncthreads();
    if (tid < 128) {
        float m = fmaxf(fmaxf(sh_red[0][tid], sh_red[1][tid]),
                        fmaxf(sh_red[2][tid], sh_red[3][tid]));
        atomicMaxFloat(&out[b * OC_ + tid], tanhf(m + cnn_b[tid]));
    }
}

// ============ fallback (small ws): monolithic fp32-gather version ============
__global__ void prep_small(const float* __restrict__ cnn_w, const float* __restrict__ att_w,
                           short* __restrict__ wsw, short* __restrict__ wsatt) {
    int i = blockIdx.x * 256 + threadIdx.x;
    if (i < OC_ * E_)  wsw[i]   = f2bf(cnn_w[i]);
    if (i < WIN_ * E_) wsatt[i] = f2bf(att_w[i]);
}

__launch_bounds__(256, 4)
__global__ void fallback_main(const int* __restrict__ x,
                              const float* __restrict__ emb,
                              const float* __restrict__ att_b_p,
                              const short* __restrict__ wsw,
                              const short* __restrict__ wsatt,
                              const float* __restrict__ cnn_b,
                              float* __restrict__ out) {
    __shared__ short sh_a[ROWS * ASTR];
    __shared__ short sh_att[16 * ASTR];
    __shared__ float sh_r[ROWS * 8];
    __shared__ float sh_score[TT];
    __shared__ int   sh_idx[8 * ROWS];

    const int tid  = threadIdx.x;
    const int lane = tid & 63;
    const int w    = tid >> 6;
    const int b    = blockIdx.y;
    const int t0   = blockIdx.x * (8 * TT);
    const int l15  = lane & 15;
    const int quad = lane >> 4;
    const int rbase = tid >> 4;
    const int c     = tid & 15;

    for (int i = tid; i < 8 * ROWS; i += 256) {
        int tile = i / ROWS, row = i - tile * ROWS;
        int t = t0 + tile * TT + row - PAD_;
        sh_idx[i] = (row < REAL_ROWS && t >= 0 && t < T_) ? x[b * T_ + t] : -1;
    }
    {
        int o = tid >> 4, cc = tid & 15;
        short8 v = (short8){0,0,0,0,0,0,0,0};
        if (o < WIN_) v = *(const short8*)(wsatt + o * E_ + cc * 8);
        *(short8*)(&sh_att[o * ASTR + cc * 8]) = v;
    }
    short8 Bf[2][4];
    #pragma unroll
    for (int j = 0; j < 2; j++)
        #pragma unroll
        for (int ks = 0; ks < 4; ks++)
            Bf[j][ks] = *(const short8*)(wsw + (size_t)(w * 32 + j * 16 + l15) * E_ + ks * 32 + quad * 8);
    __syncthreads();

    short8 g[5];
    #pragma unroll
    for (int k = 0; k < 5; k++) {
        int idx = sh_idx[rbase + 16 * k];
        short8 v = (short8){0,0,0,0,0,0,0,0};
        if (idx >= 0) {
            const float4* p = (const float4*)(emb + (size_t)idx * E_ + c * 8);
            float4 p0 = p[0], p1 = p[1];
            v = (short8){ f2bf(p0.x), f2bf(p0.y), f2bf(p0.z), f2bf(p0.w),
                          f2bf(p1.x), f2bf(p1.y), f2bf(p1.z), f2bf(p1.w) };
        }
        g[k] = v;
    }
    #pragma unroll
    for (int k = 0; k < 5; k++)
        *(short8*)(&sh_a[(rbase + 16 * k) * ASTR + c * 8]) = g[k];
    __syncthreads();

    const float attb = att_b_p[0];
    float mm[2] = { -INFINITY, -INFINITY };

    for (int it = 0; it < 8; it++) {
        for (int mt = w; mt < 5; mt += 4) {
            floatx4 acc = (floatx4){0.f, 0.f, 0.f, 0.f};
            #pragma unroll
            for (int ks = 0; ks < 4; ks++) {
                short8 a  = *(const short8*)(&sh_a[(mt * 16 + l15) * ASTR + ks * 32 + quad * 8]);
                short8 bs = *(const short8*)(&sh_att[l15 * ASTR + ks * 32 + quad * 8]);
                acc = __builtin_amdgcn_mfma_f32_16x16x32_bf16(a, bs, acc, 0, 0, 0);
            }
            if (l15 < 8) {
                #pragma unroll
                for (int r = 0; r < 4; r++)
                    sh_r[(mt * 16 + quad * 4 + r) * 8 + l15] = acc[r];
            }
        }
        __syncthreads();

        if (it + 1 < 8) {
            const int* idxp = &sh_idx[(it + 1) * ROWS];
            #pragma unroll
            for (int k = 0; k < 5; k++) {
                int idx = idxp[rbase + 16 * k];
                short8 v = (short8){0,0,0,0,0,0,0,0};
                if (idx >= 0) {
                    const float4* p = (const float4*)(emb + (size_t)idx * E_ + c * 8);
                    float4 p0 = p[0], p1 = p[1];
                    v = (short8){ f2bf(p0.x), f2bf(p0.y), f2bf(p0.z), f2bf(p0.w),
                                  f2bf(p1.x), f2bf(p1.y), f2bf(p1.z), f2bf(p1.w) };
                }
                g[k] = v;
            }
        }

        if (tid < TT) {
            float s = attb;
            #pragma unroll
            for (int k = 0; k < WIN_; k++) s += sh_r[(tid + k) * 8 + k];
            sh_score[tid] = 1.0f / (1.0f + __expf(-s));
        }

        floatx4 acc[4][2];
        #pragma unroll
        for (int i = 0; i < 4; i++)
            #pragma unroll
            for (int j = 0; j < 2; j++) acc[i][j] = (floatx4){0.f, 0.f, 0.f, 0.f};
        #pragma unroll
        for (int ks = 0; ks < 4; ks++) {
            int ko = ks * 32 + quad * 8;
            #pragma unroll
            for (int i = 0; i < 4; i++) {
                short8 ai = *(const short8*)(&sh_a[(PAD_ + i * 16 + l15) * ASTR + ko]);
                acc[i][0] = __builtin_amdgcn_mfma_f32_16x16x32_bf16(ai, Bf[0][ks], acc[i][0], 0, 0, 0);
                acc[i][1] = __builtin_amdgcn_mfma_f32_16x16x32_bf16(ai, Bf[1][ks], acc[i][1], 0, 0, 0);
            }
        }
        __syncthreads();

        #pragma unroll
        for (int i = 0; i < 4; i++) {
            #pragma unroll
            for (int r = 0; r < 4; r++) {
                float sc = sh_score[i * 16 + quad * 4 + r];
                mm[0] = fmaxf(mm[0], sc * acc[i][0][r]);
                mm[1] = fmaxf(mm[1], sc * acc[i][1][r]);
            }
        }

        if (it + 1 < 8) {
            #pragma unroll
            for (int k = 0; k < 5; k++)
                *(short8*)(&sh_a[(rbase + 16 * k) * ASTR + c * 8]) = g[k];
            __syncthreads();
        }
    }

    #pragma unroll
    for (int j = 0; j < 2; j++) {
        float m = mm[j];
        m = fmaxf(m, __shfl_xor(m, 16));
        m = fmaxf(m, __shfl_xor(m, 32));
        if (lane < 16) {
            int o = w * 32 + j * 16 + lane;
            atomicMaxFloat(&out[b * OC_ + o], tanhf(m + cnn_b[o]));
        }
    }
}

extern "C" void kernel_launch(void* const* d_in, const int* in_sizes, int n_in,
                              void* d_out, int out_size, void* d_ws, size_t ws_size,
                              hipStream_t stream) {
    const int*   x     = (const int*)d_in[0];
    const float* emb   = (const float*)d_in[1];
    const float* att_w = (const float*)d_in[2];
    const float* att_b = (const float*)d_in[3];
    const float* cnn_w = (const float*)d_in[4];
    const float* cnn_b = (const float*)d_in[5];
    float* out = (float*)d_out;

    const size_t d8_bytes = (size_t)VOCAB1 * OC_;        // int8 D table: 6400128 B
    const size_t r_bytes  = (size_t)VOCAB1 * 8 * 4;      // 1600032 B
    const size_t rs_bytes = (size_t)VOCAB1 * 4;          // 200004 B
    const size_t need = d8_bytes + r_bytes + rs_bytes + 64;

    if (ws_size >= need) {
        unsigned char* D8 = (unsigned char*)d_ws;
        float* rt = (float*)(D8 + d8_bytes);
        float* rsp = (float*)((char*)d_ws + d8_bytes + r_bytes);
        build_tables<<<(VOCAB1 + VROWS - 1) / VROWS, 256, 0, stream>>>(emb, cnn_w, att_w, D8, rt, rsp, out);
        dim3 grid(T_ / BT, B_);                           // (8, 256) = 2048 blocks
        score_max<<<grid, 256, 0, stream>>>(x, D8, rt, rsp, att_b, cnn_b, out);
    } else {
        hipMemsetAsync(d_out, 0xFF, (size_t)B_ * OC_ * sizeof(float), stream);
        short* ws_w   = (short*)d_ws;
        short* ws_att = ws_w + OC_ * E_;
        prep_small<<<16, 256, 0, stream>>>(cnn_w, att_w, ws_w, ws_att);
        dim3 grid(T_ / (8 * TT), B_);
        fallback_main<<<grid, 256, 0, stream>>>(x, emb, att_b, ws_w, ws_att, cnn_b, out);
    }
}

// Round 5
// 105.312 us; speedup vs baseline: 2.2352x; 1.0104x over previous
//
#include <hip/hip_runtime.h>
#include <hip/hip_bf16.h>
#include <math.h>

// B,T,E,WIN,OC,VOCAB = 256,2048,128,5,128,50000
#define B_   256
#define T_   2048
#define E_   128
#define WIN_ 5
#define PAD_ 2
#define OC_  128
#define VOCAB_MAX 50000
#define VOCAB1 50001
#define TT   64
#define REAL_ROWS (TT + WIN_ - 1)
#define ROWS 80
#define ASTR 136                  // LDS row stride (bf16): 272B -> 2-way alias = free
#define DSTR 132                  // fp32 D-tile stride (floats): 2-way alias max = free
#define VROWS 64                  // vocab rows per build_tables block
#define BT   256                  // tokens per score_max block

typedef __attribute__((ext_vector_type(8))) short short8;
typedef __attribute__((ext_vector_type(4))) float floatx4;
typedef __attribute__((ext_vector_type(4))) unsigned uintx4;

static __device__ __forceinline__ short f2bf(float f) {
    union { __hip_bfloat16 h; short s; } u;
    u.h = __float2bfloat16(f);
    return u.s;
}

__device__ __forceinline__ void atomicMaxFloat(float* addr, float v) {
    // requires init to -inf: works on both sign paths
    if (v >= 0.0f) atomicMax((int*)addr, __float_as_int(v));
    else           atomicMin((unsigned int*)addr, __float_as_uint(v));
}

// ============ P1: vocab-level tables (biased-u8 D + fused 16-B r-record) ============
// D8[v][o]  = round(<emb[v],cnn_w[o]> * 127/rowmax) + 128   (u8, biased)
// rrec[v]   = { f32 rowmax/127, bf16 r[0..4], pad }          (16 B, one-gather record)
// Also initializes out[] to -inf (blocks 0..127).
__launch_bounds__(256, 3)
__global__ void build_tables(const float* __restrict__ emb,
                             const float* __restrict__ cnn_w,
                             const float* __restrict__ att_w,
                             unsigned char* __restrict__ D8,
                             unsigned char* __restrict__ rrec,
                             float* __restrict__ out) {
    __shared__ __align__(16) short sh_a[VROWS * ASTR];    // 17408 B (emb tile, bf16)
    __shared__ __align__(16) float sh_df[VROWS * DSTR];   // 33792 B (D tile, fp32)
    __shared__ float sh_rf[VROWS * 8];                    // 2048 B  (r taps, fp32)
    __shared__ float sh_inv[VROWS];                       // 256 B   (127/rowmax)
    __shared__ float sh_rs[VROWS];                        // 256 B   (rowmax/127) -> ~53.7KB, 3/CU

    const int tid  = threadIdx.x;
    const int lane = tid & 63;
    const int w    = tid >> 6;
    const int l15  = lane & 15;
    const int quad = lane >> 4;
    const int v0   = blockIdx.x * VROWS;

    if (blockIdx.x < (B_ * OC_) / 256)
        out[blockIdx.x * 256 + tid] = -INFINITY;

    // stage 64 vocab rows fp32 -> bf16 (coalesced; clamp OOB rows)
    #pragma unroll
    for (int t = 0; t < 8; t++) {
        int i   = t * 256 + tid;
        int row = i >> 5, c4 = i & 31;
        int vr  = v0 + row; if (vr > VOCAB_MAX) vr = VOCAB_MAX;
        float4 v = *(const float4*)(emb + (size_t)vr * E_ + c4 * 4);
        short4 o; o.x = f2bf(v.x); o.y = f2bf(v.y); o.z = f2bf(v.z); o.w = f2bf(v.w);
        *(short4*)(&sh_a[row * ASTR + c4 * 4]) = o;
    }

    // B fragments (cnn_w fp32 -> bf16): wave w -> cols [w*32, w*32+32)
    short8 Bf[2][4];
    #pragma unroll
    for (int j = 0; j < 2; j++)
        #pragma unroll
        for (int ks = 0; ks < 4; ks++) {
            const float4* p = (const float4*)(cnn_w + (size_t)(w * 32 + j * 16 + l15) * E_ + ks * 32 + quad * 8);
            float4 p0 = p[0], p1 = p[1];
            Bf[j][ks] = (short8){ f2bf(p0.x), f2bf(p0.y), f2bf(p0.z), f2bf(p0.w),
                                  f2bf(p1.x), f2bf(p1.y), f2bf(p1.z), f2bf(p1.w) };
        }

    // att-tap fragments (taps >= WIN_ are zero)
    short8 Ba[4];
    #pragma unroll
    for (int ks = 0; ks < 4; ks++) {
        short8 v = (short8){0,0,0,0,0,0,0,0};
        if (l15 < WIN_) {
            const float4* p = (const float4*)(att_w + (size_t)l15 * E_ + ks * 32 + quad * 8);
            float4 p0 = p[0], p1 = p[1];
            v = (short8){ f2bf(p0.x), f2bf(p0.y), f2bf(p0.z), f2bf(p0.w),
                          f2bf(p1.x), f2bf(p1.y), f2bf(p1.z), f2bf(p1.w) };
        }
        Ba[ks] = v;
    }
    __syncthreads();

    // D tiles: 4 m-tiles x 2 n-tiles per wave -> fp32 staging (no bf16 re-round)
    #pragma unroll
    for (int mt = 0; mt < 4; mt++) {
        short8 a[4];
        #pragma unroll
        for (int ks = 0; ks < 4; ks++)
            a[ks] = *(const short8*)(&sh_a[(mt * 16 + l15) * ASTR + ks * 32 + quad * 8]);
        #pragma unroll
        for (int j = 0; j < 2; j++) {
            floatx4 acc = (floatx4){0.f, 0.f, 0.f, 0.f};
            #pragma unroll
            for (int ks = 0; ks < 4; ks++)
                acc = __builtin_amdgcn_mfma_f32_16x16x32_bf16(a[ks], Bf[j][ks], acc, 0, 0, 0);
            #pragma unroll
            for (int rr = 0; rr < 4; rr++)
                sh_df[(mt * 16 + quad * 4 + rr) * DSTR + w * 32 + j * 16 + l15] = acc[rr];
        }
    }

    // r tile: wave w handles m-tile w; taps land in LDS (packed later)
    {
        short8 a[4];
        #pragma unroll
        for (int ks = 0; ks < 4; ks++)
            a[ks] = *(const short8*)(&sh_a[(w * 16 + l15) * ASTR + ks * 32 + quad * 8]);
        floatx4 acc = (floatx4){0.f, 0.f, 0.f, 0.f};
        #pragma unroll
        for (int ks = 0; ks < 4; ks++)
            acc = __builtin_amdgcn_mfma_f32_16x16x32_bf16(a[ks], Ba[ks], acc, 0, 0, 0);
        if (l15 < 8) {
            #pragma unroll
            for (int rr = 0; rr < 4; rr++)
                sh_rf[(w * 16 + quad * 4 + rr) * 8 + l15] = acc[rr];
        }
    }
    __syncthreads();

    // row-max |D| (4 threads/row; partners are adjacent lanes -> shfl fold)
    {
        int row = tid >> 2, seg = tid & 3;
        const float4* p = (const float4*)(&sh_df[row * DSTR + seg * 32]);
        float m = 0.f;
        #pragma unroll
        for (int k = 0; k < 8; k++) {
            float4 v = p[k];
            m = fmaxf(m, fmaxf(fmaxf(fabsf(v.x), fabsf(v.y)), fmaxf(fabsf(v.z), fabsf(v.w))));
        }
        m = fmaxf(m, __shfl_xor(m, 1));
        m = fmaxf(m, __shfl_xor(m, 2));
        if (seg == 0) {
            sh_inv[row] = (m > 0.f) ? 127.f / m : 0.f;
            sh_rs[row]  = m * (1.f / 127.f);
        }
    }
    __syncthreads();

    // quantize (biased u8) + coalesced store: 2 iters x 256 threads x 16 B chunks
    #pragma unroll
    for (int st = 0; st < 2; st++) {
        int idx = st * 256 + tid;
        int row = idx >> 3, c8 = idx & 7;       // 8 chunks of 16 B per 128-B row
        float inv = sh_inv[row];
        const float* p = &sh_df[row * DSTR + c8 * 16];
        uintx4 outw;
        #pragma unroll
        for (int q = 0; q < 4; q++) {
            unsigned dw = 0;
            #pragma unroll
            for (int k = 0; k < 4; k++) {
                int qi = (int)rintf(p[q * 4 + k] * inv) + 128;   // biased to [1,255]
                dw |= ((unsigned)(qi & 0xFF)) << (k * 8);
            }
            outw[q] = dw;
        }
        int v = v0 + row;
        if (v <= VOCAB_MAX)
            *(uintx4*)(D8 + (size_t)v * OC_ + c8 * 16) = outw;
    }

    // fused r-record: { f32 rs, bf16 r[0..4], pad } per vocab row (16 B)
    if (tid < VROWS) {
        int v = v0 + tid;
        if (v <= VOCAB_MAX) {
            const float* rp = &sh_rf[tid * 8];
            uintx4 rec;
            rec[0] = __float_as_uint(sh_rs[tid]);
            rec[1] = (unsigned)(unsigned short)f2bf(rp[0]) |
                     ((unsigned)(unsigned short)f2bf(rp[1]) << 16);
            rec[2] = (unsigned)(unsigned short)f2bf(rp[2]) |
                     ((unsigned)(unsigned short)f2bf(rp[3]) << 16);
            rec[3] = (unsigned)(unsigned short)f2bf(rp[4]);
            *(uintx4*)(rrec + (size_t)v * 16) = rec;
        }
    }
}

// ============ P2: streaming score + max (256 tokens/block, 2048 blocks) ============
// One 16-B record gather/token for the score path (was 3 loads); biased-u8 D
// unpack is cvt+fma+max (3 VALU/value).
__launch_bounds__(256, 4)
__global__ void score_max(const int* __restrict__ x,
                          const unsigned char* __restrict__ D8,
                          const unsigned char* __restrict__ rrec,
                          const float* __restrict__ att_b_p,
                          const float* __restrict__ cnn_b,
                          float* __restrict__ out) {
    __shared__ int   sh_x[BT + 4];          // 1040 B
    __shared__ float sh_rs[BT + 4];         // 1040 B (per-token row scale)
    __shared__ float sh_rt[WIN_][BT + 8];   // 5280 B (SoA: conflict-free)
    __shared__ float sh_sc[BT];             // 1024 B (sigmoid * rowscale)
    __shared__ float sh_red[4][128];        // 2048 B -> ~10.4 KB

    const int tid  = threadIdx.x;
    const int lane = tid & 63;
    const int w    = tid >> 6;
    const int b    = blockIdx.y;
    const int t0   = blockIdx.x * BT;
    const int l7   = lane & 7;
    const int grp8 = lane >> 3;

    // phase 1: token indices + one fused record gather into LDS
    for (int i = tid; i < BT + 4; i += 256) {
        int t = t0 + i - PAD_;
        int v = (t >= 0 && t < T_) ? x[b * T_ + t] : -1;
        sh_x[i] = v;
        float rsv = 0.f, t0f = 0.f, t1f = 0.f, t2f = 0.f, t3f = 0.f, t4f = 0.f;
        if (v >= 0) {
            uintx4 rec = *(const uintx4*)(rrec + (size_t)v * 16);
            rsv = __uint_as_float(rec[0]);
            t0f = __uint_as_float(rec[1] << 16);
            t1f = __uint_as_float(rec[1] & 0xFFFF0000u);
            t2f = __uint_as_float(rec[2] << 16);
            t3f = __uint_as_float(rec[2] & 0xFFFF0000u);
            t4f = __uint_as_float(rec[3] << 16);
        }
        sh_rt[0][i] = t0f; sh_rt[1][i] = t1f; sh_rt[2][i] = t2f;
        sh_rt[3][i] = t3f; sh_rt[4][i] = t4f;
        sh_rs[i] = rsv;
    }
    __syncthreads();

    const int base_t = w * 64;              // wave owns 64 tokens

    // issue all 8 D8-gathers (wave's 64 tokens x 128 B) before the score phase
    uintx4 u[8];
    #pragma unroll
    for (int j = 0; j < 8; j++) {
        int tok = base_t + j * 8 + grp8;
        int v   = sh_x[tok + PAD_];
        u[j]    = *(const uintx4*)(D8 + (size_t)v * OC_ + l7 * 16);
    }

    // phase 2: window-sum + sigmoid, folded with rowscale (LDS only)
    {
        const float attb = att_b_p[0];
        float s = attb;
        #pragma unroll
        for (int k = 0; k < WIN_; k++) s += sh_rt[k][tid + k];
        sh_sc[tid] = sh_rs[tid + PAD_] / (1.0f + __expf(-s));
    }
    __syncthreads();

    // phase 3: max over wave's 64 tokens; lane owns cols [l7*16, l7*16+16)
    float mm[16];
    #pragma unroll
    for (int c = 0; c < 16; c++) mm[c] = -INFINITY;

    float sc8[8], nb8[8];
    #pragma unroll
    for (int j = 0; j < 8; j++) {
        sc8[j] = sh_sc[base_t + j * 8 + grp8];
        nb8[j] = -128.f * sc8[j];
    }

    #pragma unroll
    for (int j = 0; j < 8; j++) {
        #pragma unroll
        for (int q = 0; q < 4; q++) {
            unsigned dw = u[j][q];
            #pragma unroll
            for (int k = 0; k < 4; k++) {
                float val = (float)((dw >> (k * 8)) & 0xFFu);   // v_cvt_f32_ubyteN
                mm[q * 4 + k] = fmaxf(mm[q * 4 + k], fmaf(sc8[j], val, nb8[j]));
            }
        }
    }

    // fold across the 8 token-groups (lanes sharing l7)
    #pragma unroll
    for (int c = 0; c < 16; c++) {
        mm[c] = fmaxf(mm[c], __shfl_xor(mm[c], 8));
        mm[c] = fmaxf(mm[c], __shfl_xor(mm[c], 16));
        mm[c] = fmaxf(mm[c], __shfl_xor(mm[c], 32));
    }
    if (grp8 == 0) {
        #pragma unroll
        for (int c = 0; c < 16; c++) sh_red[w][l7 * 16 + c] = mm[c];
    }
    __syncthreads();
    if (tid < 128) {
        float m = fmaxf(fmaxf(sh_red[0][tid], sh_red[1][tid]),
                        fmaxf(sh_red[2][tid], sh_red[3][tid]));
        atomicMaxFloat(&out[b * OC_ + tid], tanhf(m + cnn_b[tid]));
    }
}

// ============ fallback (small ws): monolithic fp32-gather version ============
__global__ void prep_small(const float* __restrict__ cnn_w, const float* __restrict__ att_w,
                           short* __restrict__ wsw, short* __restrict__ wsatt) {
    int i = blockIdx.x * 256 + threadIdx.x;
    if (i < OC_ * E_)  wsw[i]   = f2bf(cnn_w[i]);
    if (i < WIN_ * E_) wsatt[i] = f2bf(att_w[i]);
}

__launch_bounds__(256, 4)
__global__ void fallback_main(const int* __restrict__ x,
                              const float* __restrict__ emb,
                              const float* __restrict__ att_b_p,
                              const short* __restrict__ wsw,
                              const short* __restrict__ wsatt,
                              const float* __restrict__ cnn_b,
                              float* __restrict__ out) {
    __shared__ short sh_a[ROWS * ASTR];
    __shared__ short sh_att[16 * ASTR];
    __shared__ float sh_r[ROWS * 8];
    __shared__ float sh_score[TT];
    __shared__ int   sh_idx[8 * ROWS];

    const int tid  = threadIdx.x;
    const int lane = tid & 63;
    const int w    = tid >> 6;
    const int b    = blockIdx.y;
    const int t0   = blockIdx.x * (8 * TT);
    const int l15  = lane & 15;
    const int quad = lane >> 4;
    const int rbase = tid >> 4;
    const int c     = tid & 15;

    for (int i = tid; i < 8 * ROWS; i += 256) {
        int tile = i / ROWS, row = i - tile * ROWS;
        int t = t0 + tile * TT + row - PAD_;
        sh_idx[i] = (row < REAL_ROWS && t >= 0 && t < T_) ? x[b * T_ + t] : -1;
    }
    {
        int o = tid >> 4, cc = tid & 15;
        short8 v = (short8){0,0,0,0,0,0,0,0};
        if (o < WIN_) v = *(const short8*)(wsatt + o * E_ + cc * 8);
        *(short8*)(&sh_att[o * ASTR + cc * 8]) = v;
    }
    short8 Bf[2][4];
    #pragma unroll
    for (int j = 0; j < 2; j++)
        #pragma unroll
        for (int ks = 0; ks < 4; ks++)
            Bf[j][ks] = *(const short8*)(wsw + (size_t)(w * 32 + j * 16 + l15) * E_ + ks * 32 + quad * 8);
    __syncthreads();

    short8 g[5];
    #pragma unroll
    for (int k = 0; k < 5; k++) {
        int idx = sh_idx[rbase + 16 * k];
        short8 v = (short8){0,0,0,0,0,0,0,0};
        if (idx >= 0) {
            const float4* p = (const float4*)(emb + (size_t)idx * E_ + c * 8);
            float4 p0 = p[0], p1 = p[1];
            v = (short8){ f2bf(p0.x), f2bf(p0.y), f2bf(p0.z), f2bf(p0.w),
                          f2bf(p1.x), f2bf(p1.y), f2bf(p1.z), f2bf(p1.w) };
        }
        g[k] = v;
    }
    #pragma unroll
    for (int k = 0; k < 5; k++)
        *(short8*)(&sh_a[(rbase + 16 * k) * ASTR + c * 8]) = g[k];
    __syncthreads();

    const float attb = att_b_p[0];
    float mm[2] = { -INFINITY, -INFINITY };

    for (int it = 0; it < 8; it++) {
        for (int mt = w; mt < 5; mt += 4) {
            floatx4 acc = (floatx4){0.f, 0.f, 0.f, 0.f};
            #pragma unroll
            for (int ks = 0; ks < 4; ks++) {
                short8 a  = *(const short8*)(&sh_a[(mt * 16 + l15) * ASTR + ks * 32 + quad * 8]);
                short8 bs = *(const short8*)(&sh_att[l15 * ASTR + ks * 32 + quad * 8]);
                acc = __builtin_amdgcn_mfma_f32_16x16x32_bf16(a, bs, acc, 0, 0, 0);
            }
            if (l15 < 8) {
                #pragma unroll
                for (int r = 0; r < 4; r++)
                    sh_r[(mt * 16 + quad * 4 + r) * 8 + l15] = acc[r];
            }
        }
        __syncthreads();

        if (it + 1 < 8) {
            const int* idxp = &sh_idx[(it + 1) * ROWS];
            #pragma unroll
            for (int k = 0; k < 5; k++) {
                int idx = idxp[rbase + 16 * k];
                short8 v = (short8){0,0,0,0,0,0,0,0};
                if (idx >= 0) {
                    const float4* p = (const float4*)(emb + (size_t)idx * E_ + c * 8);
                    float4 p0 = p[0], p1 = p[1];
                    v = (short8){ f2bf(p0.x), f2bf(p0.y), f2bf(p0.z), f2bf(p0.w),
                                  f2bf(p1.x), f2bf(p1.y), f2bf(p1.z), f2bf(p1.w) };
                }
                g[k] = v;
            }
        }

        if (tid < TT) {
            float s = attb;
            #pragma unroll
            for (int k = 0; k < WIN_; k++) s += sh_r[(tid + k) * 8 + k];
            sh_score[tid] = 1.0f / (1.0f + __expf(-s));
        }

        floatx4 acc[4][2];
        #pragma unroll
        for (int i = 0; i < 4; i++)
            #pragma unroll
            for (int j = 0; j < 2; j++) acc[i][j] = (floatx4){0.f, 0.f, 0.f, 0.f};
        #pragma unroll
        for (int ks = 0; ks < 4; ks++) {
            int ko = ks * 32 + quad * 8;
            #pragma unroll
            for (int i = 0; i < 4; i++) {
                short8 ai = *(const short8*)(&sh_a[(PAD_ + i * 16 + l15) * ASTR + ko]);
                acc[i][0] = __builtin_amdgcn_mfma_f32_16x16x32_bf16(ai, Bf[0][ks], acc[i][0], 0, 0, 0);
                acc[i][1] = __builtin_amdgcn_mfma_f32_16x16x32_bf16(ai, Bf[1][ks], acc[i][1], 0, 0, 0);
            }
        }
        __syncthreads();

        #pragma unroll
        for (int i = 0; i < 4; i++) {
            #pragma unroll
            for (int r = 0; r < 4; r++) {
                float sc = sh_score[i * 16 + quad * 4 + r];
                mm[0] = fmaxf(mm[0], sc * acc[i][0][r]);
                mm[1] = fmaxf(mm[1], sc * acc[i][1][r]);
            }
        }

        if (it + 1 < 8) {
            #pragma unroll
            for (int k = 0; k < 5; k++)
                *(short8*)(&sh_a[(rbase + 16 * k) * ASTR + c * 8]) = g[k];
            __syncthreads();
        }
    }

    #pragma unroll
    for (int j = 0; j < 2; j++) {
        float m = mm[j];
        m = fmaxf(m, __shfl_xor(m, 16));
        m = fmaxf(m, __shfl_xor(m, 32));
        if (lane < 16) {
            int o = w * 32 + j * 16 + lane;
            atomicMaxFloat(&out[b * OC_ + o], tanhf(m + cnn_b[o]));
        }
    }
}

extern "C" void kernel_launch(void* const* d_in, const int* in_sizes, int n_in,
                              void* d_out, int out_size, void* d_ws, size_t ws_size,
                              hipStream_t stream) {
    const int*   x     = (const int*)d_in[0];
    const float* emb   = (const float*)d_in[1];
    const float* att_w = (const float*)d_in[2];
    const float* att_b = (const float*)d_in[3];
    const float* cnn_w = (const float*)d_in[4];
    const float* cnn_b = (const float*)d_in[5];
    float* out = (float*)d_out;

    const size_t d8_bytes  = (size_t)VOCAB1 * OC_;       // u8 D table: 6400128 B (16-div)
    const size_t rec_bytes = (size_t)VOCAB1 * 16;        // fused r-records: 800016 B
    const size_t need = d8_bytes + rec_bytes + 64;

    if (ws_size >= need) {
        unsigned char* D8 = (unsigned char*)d_ws;
        unsigned char* rr = D8 + d8_bytes;
        build_tables<<<(VOCAB1 + VROWS - 1) / VROWS, 256, 0, stream>>>(emb, cnn_w, att_w, D8, rr, out);
        dim3 grid(T_ / BT, B_);                           // (8, 256) = 2048 blocks
        score_max<<<grid, 256, 0, stream>>>(x, D8, rr, att_b, cnn_b, out);
    } else {
        hipMemsetAsync(d_out, 0xFF, (size_t)B_ * OC_ * sizeof(float), stream);
        short* ws_w   = (short*)d_ws;
        short* ws_att = ws_w + OC_ * E_;
        prep_small<<<16, 256, 0, stream>>>(cnn_w, att_w, ws_w, ws_att);
        dim3 grid(T_ / (8 * TT), B_);
        fallback_main<<<grid, 256, 0, stream>>>(x, emb, att_b, ws_w, ws_att, cnn_b, out);
    }
}